// Round 1
// baseline (176.961 us; speedup 1.0000x reference)
//
#include <hip/hip_runtime.h>
#include <math.h>

#define INPUT_DIM 256
#define N_CLASSES 100
#define MAX_DEPTH 12
#define N_NODES   4095
#define N_LEAVES  4096

// ---------------------------------------------------------------------------
// Kernel 1: row-softmax of leaf_probabilities [4096 x 100] -> tab
// One wave (64 lanes) per row; lane covers cols {lane, lane+64}.
// ---------------------------------------------------------------------------
__global__ __launch_bounds__(64) void softmax_rows_kernel(
    const float* __restrict__ lp, float* __restrict__ tab) {
    const int row  = blockIdx.x;
    const int lane = threadIdx.x;
    const float* src = lp + (size_t)row * N_CLASSES;

    float v0 = src[lane];                                        // lane in [0,64) < 100
    float v1 = (lane + 64 < N_CLASSES) ? src[lane + 64] : -INFINITY;

    float m = fmaxf(v0, v1);
    #pragma unroll
    for (int off = 32; off > 0; off >>= 1) m = fmaxf(m, __shfl_xor(m, off));

    float e0 = expf(v0 - m);
    float e1 = (lane + 64 < N_CLASSES) ? expf(v1 - m) : 0.0f;
    float s = e0 + e1;
    #pragma unroll
    for (int off = 32; off > 0; off >>= 1) s += __shfl_xor(s, off);

    const float inv = 1.0f / s;
    tab[(size_t)row * N_CLASSES + lane] = e0 * inv;
    if (lane + 64 < N_CLASSES)
        tab[(size_t)row * N_CLASSES + lane + 64] = e1 * inv;
}

// ---------------------------------------------------------------------------
// Kernel 2: tree traversal, thread-per-sample. Node table staged in LDS as
// float2 {thr, feat-as-int-bits} -> one ds_read_b64 per level.
// ---------------------------------------------------------------------------
__global__ __launch_bounds__(256) void traverse_kernel(
    const float* __restrict__ x,
    const float* __restrict__ split_features,
    const float* __restrict__ split_thresholds,
    int* __restrict__ leaf_out, int batch) {
    __shared__ float2 s_nodes[N_NODES];   // .x = threshold, .y = feature (int bits)

    for (int i = threadIdx.x; i < N_NODES; i += blockDim.x) {
        int f = (int)floorf(split_features[i]);
        f = min(max(f, 0), INPUT_DIM - 1);
        float2 n;
        n.x = split_thresholds[i];
        n.y = __int_as_float(f);
        s_nodes[i] = n;
    }
    __syncthreads();

    const int b = blockIdx.x * blockDim.x + threadIdx.x;
    if (b >= batch) return;

    const float* row = x + (size_t)b * INPUT_DIM;
    int node = 0;
    #pragma unroll
    for (int d = 0; d < MAX_DEPTH; ++d) {
        const float2 n = s_nodes[node];
        const int f = __float_as_int(n.y);
        const float val = row[f];                 // scattered 4B global load
        node = 2 * node + 1 + (val > n.x ? 1 : 0);
    }
    leaf_out[b] = node - N_NODES;                 // in [0, N_LEAVES)
}

// ---------------------------------------------------------------------------
// Kernel 3: out[b, :] = tab[leaf[b], :]. Thread-per-float4 of output.
// 100 floats/row = 25 float4 -> a float4 never straddles a row boundary.
// Coalesced 16B stores; tab reads are L2-resident (1.6 MB).
// ---------------------------------------------------------------------------
__global__ __launch_bounds__(256) void gather_out_kernel(
    const float4* __restrict__ tab4,
    const int* __restrict__ leaf,
    float4* __restrict__ out4, int total4) {
    const int j = blockIdx.x * blockDim.x + threadIdx.x;
    if (j >= total4) return;
    const int r = j / 25;                  // sample (compiler magic-div)
    const int q = j - r * 25;              // float4 index within row
    out4[j] = tab4[(size_t)leaf[r] * 25 + q];
}

// ---------------------------------------------------------------------------
// Fallback (only if ws_size is too small): fully fused, per-thread softmax.
// ---------------------------------------------------------------------------
__global__ __launch_bounds__(256) void fused_kernel(
    const float* __restrict__ x,
    const float* __restrict__ split_features,
    const float* __restrict__ split_thresholds,
    const float* __restrict__ lp,
    float* __restrict__ out, int batch) {
    __shared__ float2 s_nodes[N_NODES];
    for (int i = threadIdx.x; i < N_NODES; i += blockDim.x) {
        int f = (int)floorf(split_features[i]);
        f = min(max(f, 0), INPUT_DIM - 1);
        float2 n; n.x = split_thresholds[i]; n.y = __int_as_float(f);
        s_nodes[i] = n;
    }
    __syncthreads();

    const int b = blockIdx.x * blockDim.x + threadIdx.x;
    if (b >= batch) return;

    const float* row = x + (size_t)b * INPUT_DIM;
    int node = 0;
    #pragma unroll
    for (int d = 0; d < MAX_DEPTH; ++d) {
        const float2 n = s_nodes[node];
        const float val = row[__float_as_int(n.y)];
        node = 2 * node + 1 + (val > n.x ? 1 : 0);
    }
    const int leaf = node - N_NODES;

    const float* src = lp + (size_t)leaf * N_CLASSES;
    float m = -INFINITY;
    for (int c = 0; c < N_CLASSES; ++c) m = fmaxf(m, src[c]);
    float s = 0.0f;
    float e[N_CLASSES];
    for (int c = 0; c < N_CLASSES; ++c) { e[c] = expf(src[c] - m); s += e[c]; }
    const float inv = 1.0f / s;
    float* dst = out + (size_t)b * N_CLASSES;
    for (int c = 0; c < N_CLASSES; ++c) dst[c] = e[c] * inv;
}

// ---------------------------------------------------------------------------
extern "C" void kernel_launch(void* const* d_in, const int* in_sizes, int n_in,
                              void* d_out, int out_size, void* d_ws, size_t ws_size,
                              hipStream_t stream) {
    const float* x  = (const float*)d_in[0];
    const float* sf = (const float*)d_in[1];
    const float* st = (const float*)d_in[2];
    const float* lp = (const float*)d_in[3];
    float* out = (float*)d_out;

    const int batch = in_sizes[0] / INPUT_DIM;

    const size_t tab_bytes = (size_t)N_LEAVES * N_CLASSES * sizeof(float); // 1.6384 MB
    const size_t need = tab_bytes + (size_t)batch * sizeof(int);

    if (ws_size >= need) {
        float* tab = (float*)d_ws;
        int* leaf  = (int*)((char*)d_ws + tab_bytes);

        softmax_rows_kernel<<<N_LEAVES, 64, 0, stream>>>(lp, tab);

        traverse_kernel<<<(batch + 255) / 256, 256, 0, stream>>>(
            x, sf, st, leaf, batch);

        const int total4 = batch * (N_CLASSES / 4);   // 25 float4 per row
        gather_out_kernel<<<(total4 + 255) / 256, 256, 0, stream>>>(
            (const float4*)tab, leaf, (float4*)out, total4);
    } else {
        fused_kernel<<<(batch + 255) / 256, 256, 0, stream>>>(
            x, sf, st, lp, out, batch);
    }
}

// Round 2
// 175.668 us; speedup vs baseline: 1.0074x; 1.0074x over previous
//
#include <hip/hip_runtime.h>
#include <math.h>

#define INPUT_DIM 256
#define N_CLASSES 100
#define MAX_DEPTH 12
#define N_NODES   4095
#define N_LEAVES  4096

#define TPB 256          // threads per block
#define SPT 2            // samples per thread (independent latency chains)
#define SPB (TPB * SPT)  // 512 samples per block
#define NF4 (N_CLASSES / 4)  // 25 float4 per output row

// ---------------------------------------------------------------------------
// Kernel 1: row-softmax of leaf_probabilities [4096 x 100] -> tab
// One wave (64 lanes) per row; lane covers cols {lane, lane+64}.
// ---------------------------------------------------------------------------
__global__ __launch_bounds__(64) void softmax_rows_kernel(
    const float* __restrict__ lp, float* __restrict__ tab) {
    const int row  = blockIdx.x;
    const int lane = threadIdx.x;
    const float* src = lp + (size_t)row * N_CLASSES;

    float v0 = src[lane];                                        // lane < 100
    float v1 = (lane + 64 < N_CLASSES) ? src[lane + 64] : -INFINITY;

    float m = fmaxf(v0, v1);
    #pragma unroll
    for (int off = 32; off > 0; off >>= 1) m = fmaxf(m, __shfl_xor(m, off));

    float e0 = expf(v0 - m);
    float e1 = (lane + 64 < N_CLASSES) ? expf(v1 - m) : 0.0f;
    float s = e0 + e1;
    #pragma unroll
    for (int off = 32; off > 0; off >>= 1) s += __shfl_xor(s, off);

    const float inv = 1.0f / s;
    tab[(size_t)row * N_CLASSES + lane] = e0 * inv;
    if (lane + 64 < N_CLASSES)
        tab[(size_t)row * N_CLASSES + lane + 64] = e1 * inv;
}

// ---------------------------------------------------------------------------
// Kernel 2 (fused): traverse 512 samples/block (2 chains/thread), stage leaf
// ids in LDS, then cooperatively write out[b,:] = tab[leaf[b],:] with fully
// coalesced float4 stores (consecutive threads -> consecutive float4s).
// LDS: thr 16 KB (f32, exact compares) + feat 4 KB (u8) + leaf 2 KB ~= 22.5 KB
// -> up to 7 resident blocks/CU (vs 5 before).
// ---------------------------------------------------------------------------
__global__ __launch_bounds__(TPB) void tree_fused_kernel(
    const float* __restrict__ x,
    const float* __restrict__ split_features,
    const float* __restrict__ split_thresholds,
    const float4* __restrict__ tab4,
    float4* __restrict__ out4, int batch) {
    __shared__ float         s_thr[N_NODES];
    __shared__ unsigned char s_feat[N_NODES + 1];   // +1 pad
    __shared__ int           s_leaf[SPB];

    for (int i = threadIdx.x; i < N_NODES; i += TPB) {
        s_thr[i] = split_thresholds[i];
        int f = (int)floorf(split_features[i]);
        s_feat[i] = (unsigned char)min(max(f, 0), INPUT_DIM - 1);
    }
    __syncthreads();

    const int base = blockIdx.x * SPB;

    // ---- phase B: traversal, 2 independent chains per thread ----
    const int b0 = base + threadIdx.x;
    const int b1 = b0 + TPB;
    const bool ok0 = b0 < batch;
    const bool ok1 = b1 < batch;
    const float* r0 = x + (size_t)b0 * INPUT_DIM;
    const float* r1 = x + (size_t)b1 * INPUT_DIM;

    int n0 = 0, n1 = 0;
    #pragma unroll
    for (int d = 0; d < MAX_DEPTH; ++d) {
        const int   f0 = s_feat[n0];
        const int   f1 = s_feat[n1];
        const float t0 = s_thr[n0];
        const float t1 = s_thr[n1];
        const float a0 = ok0 ? r0[f0] : 0.0f;   // two independent scattered
        const float a1 = ok1 ? r1[f1] : 0.0f;   // loads -> overlapped latency
        n0 = 2 * n0 + 1 + (a0 > t0 ? 1 : 0);
        n1 = 2 * n1 + 1 + (a1 > t1 ? 1 : 0);
    }
    s_leaf[threadIdx.x]       = n0 - N_NODES;
    s_leaf[threadIdx.x + TPB] = n1 - N_NODES;
    __syncthreads();

    // ---- phase C: coalesced output write ----
    const int nsamp = min(SPB, batch - base);         // last block may be partial
    const int maxj  = nsamp * NF4;
    const size_t gbase4 = (size_t)base * NF4;
    for (int j = threadIdx.x; j < maxj; j += TPB) {
        const int s = j / NF4;                        // magic-div by 25
        const int q = j - s * NF4;
        out4[gbase4 + j] = tab4[(size_t)s_leaf[s] * NF4 + q];
    }
}

// ---------------------------------------------------------------------------
// Fallback (ws too small): previous 3-kernel path's fused single kernel.
// ---------------------------------------------------------------------------
__global__ __launch_bounds__(256) void fused_kernel(
    const float* __restrict__ x,
    const float* __restrict__ split_features,
    const float* __restrict__ split_thresholds,
    const float* __restrict__ lp,
    float* __restrict__ out, int batch) {
    __shared__ float2 s_nodes[N_NODES];
    for (int i = threadIdx.x; i < N_NODES; i += blockDim.x) {
        int f = (int)floorf(split_features[i]);
        f = min(max(f, 0), INPUT_DIM - 1);
        float2 n; n.x = split_thresholds[i]; n.y = __int_as_float(f);
        s_nodes[i] = n;
    }
    __syncthreads();

    const int b = blockIdx.x * blockDim.x + threadIdx.x;
    if (b >= batch) return;

    const float* row = x + (size_t)b * INPUT_DIM;
    int node = 0;
    #pragma unroll
    for (int d = 0; d < MAX_DEPTH; ++d) {
        const float2 n = s_nodes[node];
        const float val = row[__float_as_int(n.y)];
        node = 2 * node + 1 + (val > n.x ? 1 : 0);
    }
    const int leaf = node - N_NODES;

    const float* src = lp + (size_t)leaf * N_CLASSES;
    float m = -INFINITY;
    for (int c = 0; c < N_CLASSES; ++c) m = fmaxf(m, src[c]);
    float s = 0.0f;
    float e[N_CLASSES];
    for (int c = 0; c < N_CLASSES; ++c) { e[c] = expf(src[c] - m); s += e[c]; }
    const float inv = 1.0f / s;
    float* dst = out + (size_t)b * N_CLASSES;
    for (int c = 0; c < N_CLASSES; ++c) dst[c] = e[c] * inv;
}

// ---------------------------------------------------------------------------
extern "C" void kernel_launch(void* const* d_in, const int* in_sizes, int n_in,
                              void* d_out, int out_size, void* d_ws, size_t ws_size,
                              hipStream_t stream) {
    const float* x  = (const float*)d_in[0];
    const float* sf = (const float*)d_in[1];
    const float* st = (const float*)d_in[2];
    const float* lp = (const float*)d_in[3];
    float* out = (float*)d_out;

    const int batch = in_sizes[0] / INPUT_DIM;

    const size_t tab_bytes = (size_t)N_LEAVES * N_CLASSES * sizeof(float); // 1.6384 MB

    if (ws_size >= tab_bytes) {
        float* tab = (float*)d_ws;

        softmax_rows_kernel<<<N_LEAVES, 64, 0, stream>>>(lp, tab);

        const int nblocks = (batch + SPB - 1) / SPB;
        tree_fused_kernel<<<nblocks, TPB, 0, stream>>>(
            x, sf, st, (const float4*)tab, (float4*)out, batch);
    } else {
        fused_kernel<<<(batch + 255) / 256, 256, 0, stream>>>(
            x, sf, st, lp, out, batch);
    }
}

// Round 4
// 152.982 us; speedup vs baseline: 1.1567x; 1.1483x over previous
//
#include <hip/hip_runtime.h>
#include <math.h>

#define INPUT_DIM 256
#define N_CLASSES 100
#define MAX_DEPTH 12
#define N_NODES   4095
#define N_LEAVES  4096

#define TPB   256              // 4 waves
#define CHUNK 24               // rows staged per chunk (6 DMA insts per wave)
#define RPW   (CHUNK / 4)      // rows per wave = 6
#define ROWP  260              // padded row stride in floats (1040 B: 16B-aligned, bank-spread)
#define NF4   (N_CLASSES / 4)  // 25 float4 per output row
#define NBLK  512              // persistent-ish grid: 2 blocks/CU

#define WAITV(N) asm volatile("s_waitcnt vmcnt(" #N ")" ::: "memory")
#define WAITLGKM() asm volatile("s_waitcnt lgkmcnt(0)" ::: "memory")

typedef float f32x4 __attribute__((ext_vector_type(4)));

__device__ __forceinline__ void async_load16(const void* gsrc, void* ldst) {
    __builtin_amdgcn_global_load_lds(
        (const __attribute__((address_space(1))) unsigned int*)gsrc,
        (__attribute__((address_space(3))) unsigned int*)ldst, 16, 0, 0);
}

// ---------------------------------------------------------------------------
// Kernel 1: row-softmax of leaf_probabilities [4096 x 100] -> tab
// ---------------------------------------------------------------------------
__global__ __launch_bounds__(64) void softmax_rows_kernel(
    const float* __restrict__ lp, float* __restrict__ tab) {
    const int row  = blockIdx.x;
    const int lane = threadIdx.x;
    const float* src = lp + (size_t)row * N_CLASSES;

    float v0 = src[lane];
    float v1 = (lane + 64 < N_CLASSES) ? src[lane + 64] : -INFINITY;

    float m = fmaxf(v0, v1);
    #pragma unroll
    for (int off = 32; off > 0; off >>= 1) m = fmaxf(m, __shfl_xor(m, off));

    float e0 = expf(v0 - m);
    float e1 = (lane + 64 < N_CLASSES) ? expf(v1 - m) : 0.0f;
    float s = e0 + e1;
    #pragma unroll
    for (int off = 32; off > 0; off >>= 1) s += __shfl_xor(s, off);

    const float inv = 1.0f / s;
    tab[(size_t)row * N_CLASSES + lane] = e0 * inv;
    if (lane + 64 < N_CLASSES)
        tab[(size_t)row * N_CLASSES + lane + 64] = e1 * inv;
}

// ---------------------------------------------------------------------------
// Kernel 2: streamed traversal. Each chunk of 24 rows (1 KB each) is DMA'd
// global->LDS (one global_load_lds_dwordx4 per row: dest = uniform row base +
// lane*16, source = per-lane row+lane*16). Double-buffered with counted
// vmcnt(6) so the next chunk's DMA stays in flight across barriers. Traversal
// is 12 dependent LDS gathers per sample (node table in LDS). Output written
// coalesced (float4, nontemporal) from the L2-resident softmax table.
// LDS: 2*24*1040 + 16380 + 4096 + 96 ~= 68.8 KB -> 2 blocks/CU.
// ---------------------------------------------------------------------------
__global__ __launch_bounds__(TPB) void tree_stream_kernel(
    const float* __restrict__ x,
    const float* __restrict__ split_features,
    const float* __restrict__ split_thresholds,
    const f32x4* __restrict__ tab4,
    f32x4* __restrict__ out4,
    int batch, int nchunks) {
    __shared__ float         s_rows[2][CHUNK][ROWP];
    __shared__ float         s_thr[N_NODES];
    __shared__ unsigned char s_feat[N_NODES + 1];
    __shared__ int           s_leaf[CHUNK];

    if (blockIdx.x >= (unsigned)nchunks) return;   // block-uniform exit

    const int tid  = threadIdx.x;
    const int wid  = tid >> 6;
    const int lane = tid & 63;

    // ---- node table -> LDS ----
    for (int i = tid; i < N_NODES; i += TPB) {
        s_thr[i] = split_thresholds[i];
        int f = (int)floorf(split_features[i]);
        s_feat[i] = (unsigned char)min(max(f, 0), INPUT_DIM - 1);
    }

    // ---- stage helper: wave `wid` DMAs rows wid*6 .. wid*6+5 of chunk c ----
    auto stage = [&](int c, int buf) {
        const int cbase = c * CHUNK;
        #pragma unroll
        for (int j = 0; j < RPW; ++j) {
            const int r = wid * RPW + j;
            int s = cbase + r;
            if (s >= batch) s = batch - 1;           // clamp: loads valid data
            const float* src = x + (size_t)s * INPUT_DIM + lane * 4;
            async_load16((const void*)src, (void*)&s_rows[buf][r][0]);
        }
    };

    const int stride = gridDim.x;
    int c = blockIdx.x;

    stage(c, 0);
    __syncthreads();          // drains node-table writes AND chunk0 DMA (vmcnt 0)

    int i = 0;
    for (; c < nchunks; c += stride, ++i) {
        const int cur = i & 1;

        // issue next chunk's DMA, then wait only for the CURRENT chunk
        const int cnext = c + stride;
        if (cnext < nchunks) {
            stage(cnext, cur ^ 1);
            WAITV(6);         // 6 newest (next-chunk DMAs) may stay in flight
        } else {
            WAITV(0);
        }
        __builtin_amdgcn_sched_barrier(0);
        __builtin_amdgcn_s_barrier();
        __builtin_amdgcn_sched_barrier(0);

        // ---- traversal: thread t -> sample t of this chunk ----
        if (tid < CHUNK) {
            const float* row = &s_rows[cur][tid][0];
            int n = 0;
            #pragma unroll
            for (int d = 0; d < MAX_DEPTH; ++d) {
                const int   f = s_feat[n];
                const float t = s_thr[n];
                n = 2 * n + 1 + (row[f] > t ? 1 : 0);
            }
            s_leaf[tid] = n - N_NODES;
        }
        WAITLGKM();           // commit s_leaf writes before barrier
        __builtin_amdgcn_sched_barrier(0);
        __builtin_amdgcn_s_barrier();
        __builtin_amdgcn_sched_barrier(0);

        // ---- coalesced output: out[b,:] = tab[leaf[b],:] ----
        const int cbase = c * CHUNK;
        const int nsamp = min(CHUNK, batch - cbase);
        const int maxj  = nsamp * NF4;
        const size_t g4 = (size_t)cbase * NF4;
        for (int j = tid; j < maxj; j += TPB) {
            const int s = j / NF4;                  // magic-div by 25
            const int q = j - s * NF4;
            f32x4 v = tab4[(size_t)s_leaf[s] * NF4 + q];
            __builtin_nontemporal_store(v, &out4[g4 + j]);
        }
        // next iteration's top barrier orders s_leaf reuse
    }
}

// ---------------------------------------------------------------------------
// Fallback (ws too small): fully fused, per-thread softmax.
// ---------------------------------------------------------------------------
__global__ __launch_bounds__(256) void fused_kernel(
    const float* __restrict__ x,
    const float* __restrict__ split_features,
    const float* __restrict__ split_thresholds,
    const float* __restrict__ lp,
    float* __restrict__ out, int batch) {
    __shared__ float2 s_nodes[N_NODES];
    for (int i = threadIdx.x; i < N_NODES; i += blockDim.x) {
        int f = (int)floorf(split_features[i]);
        f = min(max(f, 0), INPUT_DIM - 1);
        float2 n; n.x = split_thresholds[i]; n.y = __int_as_float(f);
        s_nodes[i] = n;
    }
    __syncthreads();

    const int b = blockIdx.x * blockDim.x + threadIdx.x;
    if (b >= batch) return;

    const float* row = x + (size_t)b * INPUT_DIM;
    int node = 0;
    #pragma unroll
    for (int d = 0; d < MAX_DEPTH; ++d) {
        const float2 n = s_nodes[node];
        const float val = row[__float_as_int(n.y)];
        node = 2 * node + 1 + (val > n.x ? 1 : 0);
    }
    const int leaf = node - N_NODES;

    const float* src = lp + (size_t)leaf * N_CLASSES;
    float m = -INFINITY;
    for (int cidx = 0; cidx < N_CLASSES; ++cidx) m = fmaxf(m, src[cidx]);
    float s = 0.0f;
    float e[N_CLASSES];
    for (int cidx = 0; cidx < N_CLASSES; ++cidx) { e[cidx] = expf(src[cidx] - m); s += e[cidx]; }
    const float inv = 1.0f / s;
    float* dst = out + (size_t)b * N_CLASSES;
    for (int cidx = 0; cidx < N_CLASSES; ++cidx) dst[cidx] = e[cidx] * inv;
}

// ---------------------------------------------------------------------------
extern "C" void kernel_launch(void* const* d_in, const int* in_sizes, int n_in,
                              void* d_out, int out_size, void* d_ws, size_t ws_size,
                              hipStream_t stream) {
    const float* x  = (const float*)d_in[0];
    const float* sf = (const float*)d_in[1];
    const float* st = (const float*)d_in[2];
    const float* lp = (const float*)d_in[3];
    float* out = (float*)d_out;

    const int batch = in_sizes[0] / INPUT_DIM;

    const size_t tab_bytes = (size_t)N_LEAVES * N_CLASSES * sizeof(float); // 1.6384 MB

    if (ws_size >= tab_bytes && batch > 0) {
        float* tab = (float*)d_ws;

        softmax_rows_kernel<<<N_LEAVES, 64, 0, stream>>>(lp, tab);

        const int nchunks = (batch + CHUNK - 1) / CHUNK;
        const int nblk = nchunks < NBLK ? nchunks : NBLK;
        tree_stream_kernel<<<nblk, TPB, 0, stream>>>(
            x, sf, st, (const f32x4*)tab, (f32x4*)out, batch, nchunks);
    } else {
        fused_kernel<<<(batch + 255) / 256, 256, 0, stream>>>(
            x, sf, st, lp, out, batch);
    }
}